// Round 1
// baseline (211.399 us; speedup 1.0000x reference)
//
#include <hip/hip_runtime.h>

// Problem constants
//   B=128, N=512, D=512, X(experts)=8, N_ELEM=4, N_CHG=3
//   64 output columns per atom: [0..7]=gate logits, [8..39]=pe_all (x*4+l),
//   [40..63]=pc_all (x*3+c)

#define WPACK_OFF 0        // 64 KB  : bf16 weights in B-fragment order
#define BIAS_OFF  65536    // 256 B  : fp32 bias[64]
#define G_OFF     66560    // 4 KB   : G[b][x] accumulators (128*8 fp32)
#define S_OFF     70656    // 4 KB   : S[b][x] accumulators

typedef __bf16 bf16x8 __attribute__((ext_vector_type(8)));
typedef float  f32x4  __attribute__((ext_vector_type(4)));

// ---------------------------------------------------------------------------
// prep: pack weights into MFMA-B-fragment order (bf16), pack bias, zero G/S.
// Wpack element (kc, ni, lane, j) = Wvec[col = ni*16 + (lane&15)]
//                                       [k   = kc*32 + (lane>>4)*8 + j]
// ---------------------------------------------------------------------------
__global__ __launch_bounds__(256) void prep_kernel(
    const float* __restrict__ Wg, const float* __restrict__ bg,
    const float* __restrict__ We, const float* __restrict__ be,
    const float* __restrict__ Wc, const float* __restrict__ bc,
    unsigned char* __restrict__ ws)
{
    int tid = blockIdx.x * 256 + threadIdx.x;
    __bf16* wpack = (__bf16*)(ws + WPACK_OFF);
    float*  bias  = (float*)(ws + BIAS_OFF);
    float*  gz    = (float*)(ws + G_OFF);   // G then S contiguous (2048 floats)

    if (tid < 32768) {
        int j    = tid & 7;
        int lane = (tid >> 3) & 63;
        int ni   = (tid >> 9) & 3;
        int kc   = tid >> 11;
        int col  = ni * 16 + (lane & 15);
        int k    = kc * 32 + (lane >> 4) * 8 + j;
        float v;
        if (col < 8)       v = Wg[k * 8 + col];          // Wg[k, col]
        else if (col < 40) v = We[(col - 8) * 512 + k];  // We[x,l,k], (x*4+l)=col-8
        else               v = Wc[(col - 40) * 512 + k]; // Wc[x,c,k], (x*3+c)=col-40
        wpack[tid] = (__bf16)v;
    } else if (tid < 32832) {
        int col = tid - 32768;
        float v;
        if (col < 8)       v = bg[col];
        else if (col < 40) v = be[col - 8];
        else               v = bc[col - 40];
        bias[col] = v;
    } else if (tid < 34880) {
        gz[tid - 32832] = 0.0f;
    }
}

// ---------------------------------------------------------------------------
// main: per wave — 32 atoms x 64 cols, K=512 via 16x16x32 bf16 MFMA,
// fused softmax/select/|.| epilogue, wave-reduce, atomicAdd into G/S.
// ---------------------------------------------------------------------------
__device__ inline bf16x8 load_conv(const float* __restrict__ p) {
    float4 u = *(const float4*)p;
    float4 v = *(const float4*)(p + 4);
    bf16x8 r;
    r[0] = (__bf16)u.x; r[1] = (__bf16)u.y; r[2] = (__bf16)u.z; r[3] = (__bf16)u.w;
    r[4] = (__bf16)v.x; r[5] = (__bf16)v.y; r[6] = (__bf16)v.z; r[7] = (__bf16)v.w;
    return r;
}

__global__ __launch_bounds__(256) void moe_main(
    const float* __restrict__ X, const int* __restrict__ E, const int* __restrict__ C,
    const unsigned char* __restrict__ ws,
    float* __restrict__ G, float* __restrict__ S)
{
    __shared__ float ylds[4][32 * 65];   // per-wave Y tile, padded stride 65
    __shared__ float bias_s[64];

    const int tid  = threadIdx.x;
    const int wave = tid >> 6;
    const int lane = tid & 63;
    const int quad = lane >> 4;
    const int l16  = lane & 15;

    if (tid < 64) bias_s[tid] = *((const float*)(ws + BIAS_OFF) + tid);

    const int b     = blockIdx.x >> 2;                       // 4 blocks per b
    const int atom0 = b * 512 + (blockIdx.x & 3) * 128 + wave * 32;

    const bf16x8* __restrict__ wp = (const bf16x8*)(ws + WPACK_OFF);

    // A rows for this lane: atoms atom0+l16 (mi=0) and atom0+16+l16 (mi=1)
    const float* xr0 = X + (size_t)(atom0 + l16) * 512 + quad * 8;
    const float* xr1 = xr0 + 16 * 512;

    f32x4 acc[2][4];
    #pragma unroll
    for (int mi = 0; mi < 2; ++mi)
        #pragma unroll
        for (int ni = 0; ni < 4; ++ni)
            acc[mi][ni] = 0.0f;

    for (int kc = 0; kc < 16; ++kc) {
        bf16x8 a0 = load_conv(xr0 + kc * 32);
        bf16x8 a1 = load_conv(xr1 + kc * 32);
        const bf16x8* wpk = wp + kc * 256 + lane;
        bf16x8 b0 = wpk[0];
        bf16x8 b1 = wpk[64];
        bf16x8 b2 = wpk[128];
        bf16x8 b3 = wpk[192];
        acc[0][0] = __builtin_amdgcn_mfma_f32_16x16x32_bf16(a0, b0, acc[0][0], 0, 0, 0);
        acc[0][1] = __builtin_amdgcn_mfma_f32_16x16x32_bf16(a0, b1, acc[0][1], 0, 0, 0);
        acc[0][2] = __builtin_amdgcn_mfma_f32_16x16x32_bf16(a0, b2, acc[0][2], 0, 0, 0);
        acc[0][3] = __builtin_amdgcn_mfma_f32_16x16x32_bf16(a0, b3, acc[0][3], 0, 0, 0);
        acc[1][0] = __builtin_amdgcn_mfma_f32_16x16x32_bf16(a1, b0, acc[1][0], 0, 0, 0);
        acc[1][1] = __builtin_amdgcn_mfma_f32_16x16x32_bf16(a1, b1, acc[1][1], 0, 0, 0);
        acc[1][2] = __builtin_amdgcn_mfma_f32_16x16x32_bf16(a1, b2, acc[1][2], 0, 0, 0);
        acc[1][3] = __builtin_amdgcn_mfma_f32_16x16x32_bf16(a1, b3, acc[1][3], 0, 0, 0);
    }

    // Scatter accumulators to LDS: C/D layout col=lane&15, row=(lane>>4)*4+reg
    float* Y = ylds[wave];
    #pragma unroll
    for (int mi = 0; mi < 2; ++mi)
        #pragma unroll
        for (int ni = 0; ni < 4; ++ni)
            #pragma unroll
            for (int r = 0; r < 4; ++r) {
                int row = mi * 16 + quad * 4 + r;
                int col = ni * 16 + l16;
                Y[row * 65 + col] = acc[mi][ni][r];
            }
    __syncthreads();

    float Gv[8], Sv[8];
    #pragma unroll
    for (int x = 0; x < 8; ++x) { Gv[x] = 0.0f; Sv[x] = 0.0f; }

    if (lane < 32) {
        const int atom = atom0 + lane;
        const int e = E[atom];
        const int c = C[atom];
        const float* yr = Y + lane * 65;

        float lg[8], m = -1e30f;
        #pragma unroll
        for (int x = 0; x < 8; ++x) {
            lg[x] = yr[x] + bias_s[x];
            m = fmaxf(m, lg[x]);
        }
        float sum = 0.0f;
        #pragma unroll
        for (int x = 0; x < 8; ++x) {
            lg[x] = __expf(lg[x] - m);
            sum += lg[x];
        }
        float inv = 1.0f / sum;
        #pragma unroll
        for (int x = 0; x < 8; ++x) {
            Gv[x] = lg[x] * inv;
            float pe = yr[8 + x * 4 + e] + bias_s[8 + x * 4 + e];
            float pc = yr[40 + x * 3 + c] + bias_s[40 + x * 3 + c];
            Sv[x] = pe * fabsf(pc);
        }
    }

    // 64-lane reduce (upper 32 lanes contribute zeros), then one atomic set/wave
    #pragma unroll
    for (int x = 0; x < 8; ++x) {
        float g = Gv[x], s = Sv[x];
        for (int off = 32; off > 0; off >>= 1) {
            g += __shfl_down(g, off);
            s += __shfl_down(s, off);
        }
        if (lane == 0) {
            atomicAdd(&G[b * 8 + x], g);
            atomicAdd(&S[b * 8 + x], s);
        }
    }
}

// ---------------------------------------------------------------------------
// final: out[b] = -sum_x G[b,x] * S[b,x]
// ---------------------------------------------------------------------------
__global__ void final_kernel(const unsigned char* __restrict__ ws,
                             float* __restrict__ out)
{
    int b = threadIdx.x;
    const float* G = (const float*)(ws + G_OFF);
    const float* S = (const float*)(ws + S_OFF);
    if (b < 128) {
        float s = 0.0f;
        #pragma unroll
        for (int x = 0; x < 8; ++x) s += G[b * 8 + x] * S[b * 8 + x];
        out[b] = -s;
    }
}

extern "C" void kernel_launch(void* const* d_in, const int* in_sizes, int n_in,
                              void* d_out, int out_size, void* d_ws, size_t ws_size,
                              hipStream_t stream) {
    const float* X  = (const float*)d_in[0];
    const int*   E  = (const int*)d_in[1];
    const int*   C  = (const int*)d_in[2];
    const float* Wg = (const float*)d_in[3];
    const float* bg = (const float*)d_in[4];
    const float* We = (const float*)d_in[5];
    const float* be = (const float*)d_in[6];
    const float* Wc = (const float*)d_in[7];
    const float* bc = (const float*)d_in[8];
    unsigned char* ws = (unsigned char*)d_ws;
    float* out = (float*)d_out;

    float* G = (float*)(ws + G_OFF);
    float* S = (float*)(ws + S_OFF);

    // 32768 pack + 64 bias + 2048 zero = 34880 work items -> 137 blocks
    hipLaunchKernelGGL(prep_kernel, dim3(137), dim3(256), 0, stream,
                       Wg, bg, We, be, Wc, bc, ws);
    // 65536 atoms / (4 waves * 32 atoms) = 512 blocks
    hipLaunchKernelGGL(moe_main, dim3(512), dim3(256), 0, stream,
                       X, E, C, ws, G, S);
    hipLaunchKernelGGL(final_kernel, dim3(1), dim3(128), 0, stream, ws, out);
}